// Round 1
// baseline (170.423 us; speedup 1.0000x reference)
//
#include <hip/hip_runtime.h>
#include <hip/hip_bf16.h>

#define B_DIM 16
#define T_RED 512
#define C_DIM 512

// Kernel 1: per batch, stable-compact nonzero durations, inclusive cumsum,
// then build rowsrc[b][t] = segment index (searchsorted(csum, t, 'right'))
// for t < total, -1 otherwise. One block of 512 threads per batch.
__global__ void build_rowmap(const int* __restrict__ durations,
                             int* __restrict__ rowsrc, int max_len) {
    const int b = blockIdx.x;
    const int tid = threadIdx.x;  // 0..511

    __shared__ int scan[T_RED];
    __shared__ int dcomp[T_RED];
    __shared__ int csum[T_RED];

    const int d = durations[b * T_RED + tid];
    const int f = (d > 0) ? 1 : 0;

    // Inclusive scan of flags (stable compaction positions).
    scan[tid] = f;
    __syncthreads();
    for (int off = 1; off < T_RED; off <<= 1) {
        int v = scan[tid];
        int add = (tid >= off) ? scan[tid - off] : 0;
        __syncthreads();
        scan[tid] = v + add;
        __syncthreads();
    }

    // Compacted durations: nonzeros packed to front (stable), zeros at tail.
    dcomp[tid] = 0;
    __syncthreads();
    if (f) dcomp[scan[tid] - 1] = d;
    __syncthreads();

    // Inclusive cumsum of compacted durations.
    csum[tid] = dcomp[tid];
    __syncthreads();
    for (int off = 1; off < T_RED; off <<= 1) {
        int v = csum[tid];
        int add = (tid >= off) ? csum[tid - off] : 0;
        __syncthreads();
        csum[tid] = v + add;
        __syncthreads();
    }

    const int total = csum[T_RED - 1];  // == target_T[b]
    const int myd   = dcomp[tid];
    const int start = csum[tid] - myd;

    // Scatter: output rows [start, start+myd) map to segment index `tid`.
    // Segments tile [0, total) exactly; total <= max_len by construction.
    for (int k = 0; k < myd; ++k)
        rowsrc[b * max_len + start + k] = tid;

    // Tail: invalid rows.
    for (int t = total + tid; t < max_len; t += T_RED)
        rowsrc[b * max_len + t] = -1;
}

// Kernel 2: one 128-thread block per output row; float4 copy or zero-fill.
// grid = (max_len, B). Thread 0 writes the mask (as float 0/1).
__global__ void scatter_rows(const float* __restrict__ x,
                             const int* __restrict__ rowsrc,
                             float* __restrict__ out_x,
                             float* __restrict__ out_mask,
                             int max_len) {
    const int t = blockIdx.x;
    const int b = blockIdx.y;
    const int c4 = threadIdx.x;  // 0..127, each handles 4 floats

    const int src = rowsrc[b * max_len + t];

    float4 v = make_float4(0.f, 0.f, 0.f, 0.f);
    if (src >= 0) {
        v = ((const float4*)x)[(size_t)(b * T_RED + src) * (C_DIM / 4) + c4];
    }
    ((float4*)out_x)[((size_t)b * max_len + t) * (C_DIM / 4) + c4] = v;

    if (c4 == 0) {
        out_mask[(size_t)b * max_len + t] = (src >= 0) ? 0.0f : 1.0f;
    }
}

extern "C" void kernel_launch(void* const* d_in, const int* in_sizes, int n_in,
                              void* d_out, int out_size, void* d_ws, size_t ws_size,
                              hipStream_t stream) {
    // Inputs (setup_inputs order): pooled_x (B,T_RED,C) f32, durations (B,T_RED) i32,
    // target_T (B,) i32 (unused: total == target_T per batch).
    const float* pooled_x  = (const float*)d_in[0];
    const int*   durations = (const int*)d_in[1];

    // out_size = B*max_len*C + B*max_len  ->  max_len = out_size / (B*(C+1))
    const int max_len = out_size / (B_DIM * (C_DIM + 1));

    float* out_x    = (float*)d_out;
    float* out_mask = out_x + (size_t)B_DIM * max_len * C_DIM;

    int* rowsrc = (int*)d_ws;  // B * max_len ints

    build_rowmap<<<B_DIM, T_RED, 0, stream>>>(durations, rowsrc, max_len);

    dim3 grid(max_len, B_DIM);
    scatter_rows<<<grid, C_DIM / 4, 0, stream>>>(pooled_x, rowsrc, out_x, out_mask, max_len);
}

// Round 2
// 160.703 us; speedup vs baseline: 1.0605x; 1.0605x over previous
//
#include <hip/hip_runtime.h>
#include <hip/hip_bf16.h>

#define B_DIM 16
#define T_RED 512
#define C_DIM 512

__device__ inline int wave_incl_scan(int v) {
    // inclusive scan within a 64-lane wave via shfl_up
    #pragma unroll
    for (int off = 1; off < 64; off <<= 1) {
        int n = __shfl_up(v, off, 64);
        if ((threadIdx.x & 63) >= off) v += n;
    }
    return v;
}

// Block-wide inclusive scan for 512 threads (8 waves). Returns inclusive sum.
__device__ inline int block_incl_scan(int v, int* wsum /*>=8 ints LDS*/) {
    const int lane = threadIdx.x & 63;
    const int wid  = threadIdx.x >> 6;   // 0..7
    int s = wave_incl_scan(v);
    if (lane == 63) wsum[wid] = s;
    __syncthreads();
    if (wid == 0 && lane < 8) {
        int w = wsum[lane];
        #pragma unroll
        for (int off = 1; off < 8; off <<= 1) {
            int n = __shfl_up(w, off, 8);
            if (lane >= off) w += n;
        }
        wsum[lane] = w;
    }
    __syncthreads();
    if (wid > 0) s += wsum[wid - 1];
    return s;
}

// Kernel 1: per batch, stable-compact nonzero durations, inclusive cumsum,
// then build rowsrc[b*max_len + t] = ABSOLUTE source row (b*T_RED + seg)
// for t < total, -1 otherwise. One block of 512 threads per batch.
__global__ void build_rowmap(const int* __restrict__ durations,
                             int* __restrict__ rowsrc, int max_len) {
    const int b = blockIdx.x;
    const int tid = threadIdx.x;  // 0..511

    __shared__ int wsum[8];
    __shared__ int dcomp[T_RED];
    __shared__ int csum_s[T_RED];

    const int d = durations[b * T_RED + tid];
    const int f = (d > 0) ? 1 : 0;

    // Stable compaction position.
    const int pos = block_incl_scan(f, wsum);   // inclusive count of flags
    dcomp[tid] = 0;
    __syncthreads();
    if (f) dcomp[pos - 1] = d;
    __syncthreads();

    // Inclusive cumsum of compacted durations.
    const int myd = dcomp[tid];
    __syncthreads();
    const int cs = block_incl_scan(myd, wsum);
    csum_s[tid] = cs;
    __syncthreads();

    const int total = csum_s[T_RED - 1];  // == target_T[b]
    const int start = cs - myd;
    const int srcrow = b * T_RED + tid;   // absolute row in pooled_x

    // Output rows [start, start+myd) map to this segment.
    for (int k = 0; k < myd; ++k)
        rowsrc[b * max_len + start + k] = srcrow;

    // Tail: invalid rows.
    for (int t = total + tid; t < max_len; t += T_RED)
        rowsrc[b * max_len + t] = -1;
}

// Kernel 2: 256 threads per block, 4 rows per block (2 independent rows per
// thread for ILP). rowsrc holds absolute source rows, so no division needed.
__global__ void scatter_rows(const float4* __restrict__ x4,
                             const int* __restrict__ rowsrc,
                             float4* __restrict__ out4,
                             float* __restrict__ out_mask,
                             int nrows) {
    const int sub = threadIdx.x >> 7;   // 0..1
    const int c4  = threadIdx.x & 127;  // 0..127
    const int r0  = blockIdx.x * 4 + sub;
    const int r1  = r0 + 2;

    const int s0 = (r0 < nrows) ? rowsrc[r0] : -1;
    const int s1 = (r1 < nrows) ? rowsrc[r1] : -1;

    float4 v0 = make_float4(0.f, 0.f, 0.f, 0.f);
    float4 v1 = make_float4(0.f, 0.f, 0.f, 0.f);
    if (s0 >= 0) v0 = x4[(size_t)s0 * (C_DIM / 4) + c4];
    if (s1 >= 0) v1 = x4[(size_t)s1 * (C_DIM / 4) + c4];

    if (r0 < nrows) out4[(size_t)r0 * (C_DIM / 4) + c4] = v0;
    if (r1 < nrows) out4[(size_t)r1 * (C_DIM / 4) + c4] = v1;

    if (c4 == 0) {
        if (r0 < nrows) out_mask[r0] = (s0 >= 0) ? 0.0f : 1.0f;
        if (r1 < nrows) out_mask[r1] = (s1 >= 0) ? 0.0f : 1.0f;
    }
}

extern "C" void kernel_launch(void* const* d_in, const int* in_sizes, int n_in,
                              void* d_out, int out_size, void* d_ws, size_t ws_size,
                              hipStream_t stream) {
    // Inputs: pooled_x (B,T_RED,C) f32, durations (B,T_RED) i32, target_T (B,) i32.
    const float* pooled_x  = (const float*)d_in[0];
    const int*   durations = (const int*)d_in[1];

    // out_size = B*max_len*C + B*max_len  ->  max_len = out_size / (B*(C+1))
    const int max_len = out_size / (B_DIM * (C_DIM + 1));
    const int nrows   = B_DIM * max_len;

    float* out_x    = (float*)d_out;
    float* out_mask = out_x + (size_t)nrows * C_DIM;

    int* rowsrc = (int*)d_ws;  // nrows ints

    build_rowmap<<<B_DIM, T_RED, 0, stream>>>(durations, rowsrc, max_len);

    scatter_rows<<<(nrows + 3) / 4, 256, 0, stream>>>(
        (const float4*)pooled_x, rowsrc, (float4*)out_x, out_mask, nrows);
}